// Round 4
// baseline (2333.881 us; speedup 1.0000x reference)
//
#include <hip/hip_runtime.h>

#define THREADS 256
#define BSHIFT 7                    // 128 nodes per bucket
#define BNODES 128
#define REPS 32                     // cursor replicas per bucket
#define SCHUNK 25                   // vb_scan elements per thread (1024*25 >= NVB+1)

typedef __attribute__((ext_vector_type(8))) short short8;
typedef __attribute__((ext_vector_type(4))) float f32x4;

__device__ inline unsigned short f2bf(float f) {
  unsigned int u = __float_as_uint(f);
  unsigned int r = u + 0x7fffu + ((u >> 16) & 1u);  // round-to-nearest-even
  return (unsigned short)(r >> 16);
}

// ---------------- replicated binning ----------------
// vb = bucket*REPS + (blockIdx & (REPS-1)); count and fill use identical grids,
// so each edge maps to the same vb in both kernels.

__global__ void bucket_count(const int* __restrict__ dst, int* __restrict__ bcnt, int E) {
  int e = blockIdx.x * blockDim.x + threadIdx.x;
  if (e < E)
    atomicAdd(&bcnt[(dst[e] >> BSHIFT) * REPS + (blockIdx.x & (REPS - 1))], 1);
}

// single block, 1024 threads: exclusive scan of bcnt[0..NVB) -> boff & bcur; boff[NVB]=E
__global__ __launch_bounds__(1024) void vb_scan(const int* __restrict__ bcnt,
                                                int* __restrict__ boff,
                                                int* __restrict__ bcur, int NVB) {
  __shared__ int s[1024];
  int t = threadIdx.x;
  int base = t * SCHUNK;
  int loc[SCHUNK];
  int sum = 0;
#pragma unroll
  for (int i = 0; i < SCHUNK; ++i) {
    int idx = base + i;
    loc[i] = sum;
    sum += (idx < NVB) ? bcnt[idx] : 0;
  }
  s[t] = sum;
  __syncthreads();
  for (int d = 1; d < 1024; d <<= 1) {
    int x = (t >= d) ? s[t - d] : 0;
    __syncthreads();
    s[t] += x;
    __syncthreads();
  }
  int pre = s[t] - sum;
#pragma unroll
  for (int i = 0; i < SCHUNK; ++i) {
    int idx = base + i;
    if (idx <= NVB) { int v = pre + loc[i]; boff[idx] = v; bcur[idx] = v; }
  }
}

// append packed records: (dst & 127) << 17 | src   (src < 2^17)
__global__ void bin_fill(const int* __restrict__ src, const int* __restrict__ dst,
                         int* __restrict__ bcur, unsigned* __restrict__ bins, int E) {
  int e = blockIdx.x * blockDim.x + threadIdx.x;
  if (e < E) {
    int d = dst[e];
    int vb = (d >> BSHIFT) * REPS + (blockIdx.x & (REPS - 1));
    int pos = atomicAdd(&bcur[vb], 1);
    bins[pos] = ((unsigned)(d & (BNODES - 1)) << 17) | (unsigned)src[e];
  }
}

// one block per bucket: per-node degree via LDS histogram -> invdeg
__global__ __launch_bounds__(256) void node_invdeg(const unsigned* __restrict__ bins,
                                                   const int* __restrict__ boff,
                                                   float* __restrict__ invdeg, int N) {
  __shared__ int lcnt[BNODES];
  int b = blockIdx.x, t = threadIdx.x;
  if (t < BNODES) lcnt[t] = 0;
  __syncthreads();
  int beg = boff[b * REPS], end = boff[b * REPS + REPS];
  for (int i = beg + t; i < end; i += 256) atomicAdd(&lcnt[bins[i] >> 17], 1);
  __syncthreads();
  int g = b * BNODES + t;
  if (t < BNODES && g < N) invdeg[g] = 1.0f / (float)(lcnt[t] > 1 ? lcnt[t] : 1);
}

// ---------------- fused bucket mean-aggregate ----------------
// One block per bucket. 32KB LDS fp32 accumulator [128 nodes][64 ch].
// Full wave per edge: lane = channel; ds_add_f32 bank-conflict-free.
// Epilogue: v = accum*invdeg (+add) (+bias) (relu) -> bf16 or fp32.

__global__ __launch_bounds__(256) void agg_bucket(
    const unsigned short* __restrict__ feat, const unsigned* __restrict__ bins,
    const int* __restrict__ boff, const float* __restrict__ invdeg,
    const unsigned short* __restrict__ add, const float* __restrict__ bias,
    void* __restrict__ outv, int N, int relu, int out_fp32)
{
  __shared__ float accum[BNODES * 64];
  int b = blockIdx.x, t = threadIdx.x;
  for (int i = t; i < BNODES * 64; i += 256) accum[i] = 0.f;
  __syncthreads();

  int beg = boff[b * REPS], end = boff[b * REPS + REPS];
  int wid = t >> 6, lane = t & 63;

  for (int i0 = beg + wid * 8; i0 < end; i0 += 32) {
    unsigned rec[8];
    float f[8];
#pragma unroll
    for (int u = 0; u < 8; ++u) {
      int i = i0 + u;
      rec[u] = (i < end) ? bins[i] : 0u;
    }
#pragma unroll
    for (int u = 0; u < 8; ++u) {
      unsigned s = rec[u] & 0x1FFFFu;
      unsigned short h = feat[(size_t)s * 64 + lane];
      float v = __uint_as_float((unsigned)h << 16);
      f[u] = ((i0 + u) < end) ? v : 0.f;   // invalid -> add 0 to node 0 (harmless)
    }
#pragma unroll
    for (int u = 0; u < 8; ++u)
      atomicAdd(&accum[(rec[u] >> 17) * 64 + lane], f[u]);
  }
  __syncthreads();

  for (int i = t; i < BNODES * 64; i += 256) {
    int n = i >> 6, c = i & 63;
    int g = b * BNODES + n;
    if (g >= N) continue;
    float v = accum[i] * invdeg[g];
    if (add) {
      unsigned short h = add[(size_t)g * 64 + c];
      v += __uint_as_float((unsigned)h << 16);
    }
    if (bias) v += bias[c];
    if (relu) v = fmaxf(v, 0.f);
    if (out_fp32) ((float*)outv)[(size_t)g * 64 + c] = v;
    else          ((unsigned short*)outv)[(size_t)g * 64 + c] = f2bf(v);
  }
}

// ---------------- MFMA GEMM: C[N,128] = A[N,128] @ Weff[128,128]^T ------------------
// wmode 0 (out-concat): Weff[c][k] = c<64 ? W0[c][k] (W0=[64,128]) : W1[c-64][k]
// wmode 1 (K-concat)  : Weff[c][k] = k<64 ? W0[c][k] (W0=[128,64]) : W1[c][k-64]

__global__ __launch_bounds__(256) void mfma_gemm(
    const void* __restrict__ A0_, const void* __restrict__ A1_, int sa0b, int sa1b, int a_fp32,
    const float* __restrict__ W0, const float* __restrict__ W1, int wmode,
    const float* __restrict__ bias, int relu,
    unsigned short* __restrict__ out0, unsigned short* __restrict__ out1,
    int so0, int so1, int N)
{
  __shared__ __align__(16) unsigned char Wlds[128 * 256];  // Weff[c][k] bf16, XOR-swizzled
  int t = threadIdx.x;

#pragma unroll
  for (int it = 0; it < 8; ++it) {
    int i = it * 256 + t;
    int c = i >> 4, kg = i & 15;
    const float* src;
    if (wmode == 0) src = (c < 64) ? (W0 + c * 128 + kg * 8) : (W1 + (c - 64) * 128 + kg * 8);
    else            src = (kg < 8) ? (W0 + c * 64 + kg * 8)  : (W1 + c * 64 + (kg - 8) * 8);
    short8 v;
#pragma unroll
    for (int q = 0; q < 8; ++q) v[q] = (short)f2bf(src[q]);
    *(short8*)(&Wlds[c * 256 + ((kg * 16) ^ ((c & 7) << 4))]) = v;
  }
  __syncthreads();

  int w = t >> 6, l = t & 63;
  int lr = l & 15, lk = l >> 4;
  int r0 = blockIdx.x * 128 + w * 32;

  short8 afr[2][4];
#pragma unroll
  for (int set = 0; set < 2; ++set) {
    int row = r0 + set * 16 + lr;
    bool ok = row < N;
    if (a_fp32) {
#pragma unroll
      for (int kt = 0; kt < 4; ++kt) {
        short8 a = {0, 0, 0, 0, 0, 0, 0, 0};
        if (ok) {
          const unsigned char* bp = (const unsigned char*)(kt < 2 ? A0_ : A1_)
                + (size_t)row * (kt < 2 ? sa0b : sa1b) + 32 * lk + 128 * (kt & 1);
          f32x4 f0 = *(const f32x4*)bp;
          f32x4 f1 = *(const f32x4*)(bp + 16);
#pragma unroll
          for (int q = 0; q < 4; ++q) { a[q] = (short)f2bf(f0[q]); a[q + 4] = (short)f2bf(f1[q]); }
        }
        afr[set][kt] = a;
      }
    } else {
#pragma unroll
      for (int kt = 0; kt < 4; ++kt) {
        short8 a = {0, 0, 0, 0, 0, 0, 0, 0};
        if (ok) {
          const unsigned char* bp = (const unsigned char*)(kt < 2 ? A0_ : A1_)
                + (size_t)row * (kt < 2 ? sa0b : sa1b) + 16 * lk + 64 * (kt & 1);
          a = *(const short8*)bp;
        }
        afr[set][kt] = a;
      }
    }
  }

  f32x4 acc[2][8];
#pragma unroll
  for (int s = 0; s < 2; ++s)
#pragma unroll
    for (int c = 0; c < 8; ++c) acc[s][c] = (f32x4){0.f, 0.f, 0.f, 0.f};

#pragma unroll
  for (int ct = 0; ct < 8; ++ct) {
    int c = ct * 16 + lr;
    const unsigned char* rowp = &Wlds[c * 256];
    unsigned swz = (unsigned)((c & 7) << 4);
    short8 bfr[4];
#pragma unroll
    for (int kt = 0; kt < 4; ++kt)
      bfr[kt] = *(const short8*)(rowp + (((unsigned)(16 * lk + 64 * kt)) ^ swz));
#pragma unroll
    for (int kt = 0; kt < 4; ++kt) {
      acc[0][ct] = __builtin_amdgcn_mfma_f32_16x16x32_bf16(afr[0][kt], bfr[kt], acc[0][ct], 0, 0, 0);
      acc[1][ct] = __builtin_amdgcn_mfma_f32_16x16x32_bf16(afr[1][kt], bfr[kt], acc[1][ct], 0, 0, 0);
    }
  }

#pragma unroll
  for (int set = 0; set < 2; ++set) {
    int rbase = r0 + set * 16 + lk * 4;
#pragma unroll
    for (int ct = 0; ct < 8; ++ct) {
      int col = ct * 16 + lr;
      unsigned short* outp = (col < 64) ? out0 : out1;
      int so = (col < 64) ? so0 : so1;
      int cb = (col < 64) ? col : col - 64;
      float bv = bias ? bias[col] : 0.f;
#pragma unroll
      for (int j = 0; j < 4; ++j) {
        int row = rbase + j;
        if (row < N) {
          float v = acc[set][ct][j] + bv;
          if (relu) v = fmaxf(v, 0.f);
          outp[(size_t)row * so + cb] = f2bf(v);
        }
      }
    }
  }
}

// ---------------- launch ----------------

extern "C" void kernel_launch(void* const* d_in, const int* in_sizes, int n_in,
                              void* d_out, int out_size, void* d_ws, size_t ws_size,
                              hipStream_t stream) {
  const float* x   = (const float*)d_in[0];
  const int* edges = (const int*)d_in[1];
  const float* Wl1 = (const float*)d_in[2];
  const float* Wr1 = (const float*)d_in[3];
  const float* b1  = (const float*)d_in[4];
  const float* Wl2 = (const float*)d_in[5];
  const float* Wr2 = (const float*)d_in[6];
  const float* b2  = (const float*)d_in[7];
  const float* Wl3 = (const float*)d_in[8];
  const float* Wr3 = (const float*)d_in[9];
  const float* b3  = (const float*)d_in[10];

  int N = in_sizes[0] / 128;
  int E = in_sizes[1] / 2;
  const int* srcp = edges;
  const int* dstp = edges + E;
  int NBK = (N + BNODES - 1) / BNODES;   // 782 buckets for N=100k
  int NVB = NBK * REPS;                  // 25024 virtual buckets

  char* ws = (char*)d_ws;
  size_t off = 0;
  auto carve = [&](size_t bytes) -> void* {
    void* p = (void*)(ws + off);
    off += (bytes + 255) & ~(size_t)255;
    return p;
  };
  unsigned* bins = (unsigned*)carve((size_t)E * 4);
  int*   bcnt   = (int*)carve((size_t)NVB * 4);
  int*   boffb  = (int*)carve((size_t)(NVB + 1) * 4);
  int*   bcur   = (int*)carve((size_t)(NVB + 1) * 4);
  float* invdeg = (float*)carve((size_t)N * 4);
  unsigned short* B1 = (unsigned short*)carve((size_t)N * 64 * 2);
  unsigned short* B2 = (unsigned short*)carve((size_t)N * 64 * 2);
  unsigned short* B3 = (unsigned short*)carve((size_t)N * 64 * 2);
  unsigned short* P  = (unsigned short*)carve((size_t)N * 128 * 2);
  (void)ws_size;

  hipMemsetAsync(bcnt, 0, (size_t)NVB * 4, stream);

  int gridE = (E + THREADS - 1) / THREADS;

  bucket_count<<<gridE, THREADS, 0, stream>>>(dstp, bcnt, E);
  vb_scan<<<1, 1024, 0, stream>>>(bcnt, boffb, bcur, NVB);
  bin_fill<<<gridE, THREADS, 0, stream>>>(srcp, dstp, bcur, bins, E);
  node_invdeg<<<NBK, THREADS, 0, stream>>>(bins, boffb, invdeg, N);

  int gridG = (N + 127) / 128;

  // Layer 1 (transform-first): [z1|y1] = x @ [Wl1|Wr1]^T -> B1(z1), B2(y1)   [A fp32]
  mfma_gemm<<<gridG, THREADS, 0, stream>>>(x, x + 64, 512, 512, 1, Wl1, Wr1, 0,
                                           nullptr, 0, B1, B2, 64, 64, N);
  // h1 = relu(mean(z1) + y1 + b1) -> B3
  agg_bucket<<<NBK, THREADS, 0, stream>>>(B1, bins, boffb, invdeg, B2, b1, B3, N, 1, 0);
  // mean2 = mean(h1) -> B1
  agg_bucket<<<NBK, THREADS, 0, stream>>>(B3, bins, boffb, invdeg, nullptr, nullptr, B1, N, 0, 0);
  // Layer 2 (aggregate-first): h2 = relu([mean2|h1] @ [Wl2,Wr2]_K^T + b2) -> P
  mfma_gemm<<<gridG, THREADS, 0, stream>>>(B1, B3, 128, 128, 0, Wl2, Wr2, 1,
                                           b2, 1, P, P + 64, 128, 128, N);
  // Layer 3 (transform-first): [z3|y3] = h2 @ [Wl3|Wr3]^T -> B2(z3), B1(y3)
  mfma_gemm<<<gridG, THREADS, 0, stream>>>(P, P + 64, 256, 256, 0, Wl3, Wr3, 0,
                                           nullptr, 0, B2, B1, 64, 64, N);
  // out = mean(z3) + y3 + b3 -> d_out (fp32)
  agg_bucket<<<NBK, THREADS, 0, stream>>>(B2, bins, boffb, invdeg, B1, b3, d_out, N, 0, 1);
}

// Round 5
// 417.604 us; speedup vs baseline: 5.5887x; 5.5887x over previous
//
#include <hip/hip_runtime.h>

#define THREADS 256
#define BSHIFT 7                    // 128 nodes per bucket
#define BNODES 128
#define REPS 32                     // cursor replicas per bucket
#define SCHUNK 25                   // vb_scan elements per thread (1024*25 >= NVB+1)

typedef __attribute__((ext_vector_type(8))) short short8;
typedef __attribute__((ext_vector_type(4))) float f32x4;

__device__ inline unsigned short f2bf(float f) {
  unsigned int u = __float_as_uint(f);
  unsigned int r = u + 0x7fffu + ((u >> 16) & 1u);  // round-to-nearest-even
  return (unsigned short)(r >> 16);
}

// ---------------- replicated binning ----------------
// vb = bucket*REPS + (blockIdx & (REPS-1)); count and fill use identical grids,
// so each edge maps to the same vb in both kernels.

__global__ void bucket_count(const int* __restrict__ dst, int* __restrict__ bcnt, int E) {
  int e = blockIdx.x * blockDim.x + threadIdx.x;
  if (e < E)
    atomicAdd(&bcnt[(dst[e] >> BSHIFT) * REPS + (blockIdx.x & (REPS - 1))], 1);
}

// single block, 1024 threads: exclusive scan of bcnt[0..NVB) -> boff & bcur; boff[NVB]=E
__global__ __launch_bounds__(1024) void vb_scan(const int* __restrict__ bcnt,
                                                int* __restrict__ boff,
                                                int* __restrict__ bcur, int NVB) {
  __shared__ int s[1024];
  int t = threadIdx.x;
  int base = t * SCHUNK;
  int loc[SCHUNK];
  int sum = 0;
#pragma unroll
  for (int i = 0; i < SCHUNK; ++i) {
    int idx = base + i;
    loc[i] = sum;
    sum += (idx < NVB) ? bcnt[idx] : 0;
  }
  s[t] = sum;
  __syncthreads();
  for (int d = 1; d < 1024; d <<= 1) {
    int x = (t >= d) ? s[t - d] : 0;
    __syncthreads();
    s[t] += x;
    __syncthreads();
  }
  int pre = s[t] - sum;
#pragma unroll
  for (int i = 0; i < SCHUNK; ++i) {
    int idx = base + i;
    if (idx <= NVB) { int v = pre + loc[i]; boff[idx] = v; bcur[idx] = v; }
  }
}

// append packed records: (dst & 127) << 17 | src   (src < 2^17)
__global__ void bin_fill(const int* __restrict__ src, const int* __restrict__ dst,
                         int* __restrict__ bcur, unsigned* __restrict__ bins, int E) {
  int e = blockIdx.x * blockDim.x + threadIdx.x;
  if (e < E) {
    int d = dst[e];
    int vb = (d >> BSHIFT) * REPS + (blockIdx.x & (REPS - 1));
    int pos = atomicAdd(&bcur[vb], 1);
    bins[pos] = ((unsigned)(d & (BNODES - 1)) << 17) | (unsigned)src[e];
  }
}

// one block per bucket: per-node degree histogram -> rowoff (bucket-local scan) + invdeg
__global__ __launch_bounds__(256) void node_offsets(
    const unsigned* __restrict__ bins, const int* __restrict__ boff,
    int* __restrict__ rowoff, float* __restrict__ invdeg, int N, int E) {
  __shared__ int lcnt[BNODES];
  __shared__ int lscan[BNODES];
  int b = blockIdx.x, t = threadIdx.x;
  if (t < BNODES) lcnt[t] = 0;
  __syncthreads();
  int beg = boff[b * REPS], end = boff[b * REPS + REPS];
  for (int i = beg + t; i < end; i += 256) atomicAdd(&lcnt[bins[i] >> 17], 1);
  __syncthreads();
  if (t < BNODES) lscan[t] = lcnt[t];
  __syncthreads();
  for (int d = 1; d < BNODES; d <<= 1) {
    int v = (t < BNODES && t >= d) ? lscan[t - d] : 0;
    __syncthreads();
    if (t < BNODES) lscan[t] += v;
    __syncthreads();
  }
  if (t < BNODES) {
    int g = b * BNODES + t;
    if (g < N) {
      rowoff[g] = beg + lscan[t] - lcnt[t];   // exclusive within bucket
      invdeg[g] = 1.0f / (float)(lcnt[t] > 1 ? lcnt[t] : 1);
    }
  }
  if (b == 0 && t == 0) rowoff[N] = E;
}

// one block per bucket: CSR fill with LDS cursors; adj writes land in a ~8KB window
__global__ __launch_bounds__(256) void csr_fill(
    const unsigned* __restrict__ bins, const int* __restrict__ boff,
    const int* __restrict__ rowoff, int* __restrict__ adj, int N) {
  __shared__ int lrow[BNODES];
  __shared__ int lcur[BNODES];
  int b = blockIdx.x, t = threadIdx.x;
  if (t < BNODES) {
    int g = b * BNODES + t;
    lrow[t] = (g < N) ? rowoff[g] : 0;
    lcur[t] = 0;
  }
  __syncthreads();
  int beg = boff[b * REPS], end = boff[b * REPS + REPS];
  for (int i = beg + t; i < end; i += 256) {
    unsigned v = bins[i];
    int n = v >> 17;
    int pos = atomicAdd(&lcur[n], 1);
    adj[lrow[n] + pos] = (int)(v & 0x1FFFFu);
  }
}

// ---------------- MFMA GEMM: C[N,128] = A[N,128] @ Weff[128,128]^T ------------------
// wmode 0 (out-concat): Weff[c][k] = c<64 ? W0[c][k] (W0=[64,128]) : W1[c-64][k]
// wmode 1 (K-concat)  : Weff[c][k] = k<64 ? W0[c][k] (W0=[128,64]) : W1[c][k-64]

__global__ __launch_bounds__(256) void mfma_gemm(
    const void* __restrict__ A0_, const void* __restrict__ A1_, int sa0b, int sa1b, int a_fp32,
    const float* __restrict__ W0, const float* __restrict__ W1, int wmode,
    const float* __restrict__ bias, int relu,
    unsigned short* __restrict__ out0, unsigned short* __restrict__ out1,
    int so0, int so1, int N)
{
  __shared__ __align__(16) unsigned char Wlds[128 * 256];  // Weff[c][k] bf16, XOR-swizzled
  int t = threadIdx.x;

#pragma unroll
  for (int it = 0; it < 8; ++it) {
    int i = it * 256 + t;
    int c = i >> 4, kg = i & 15;
    const float* src;
    if (wmode == 0) src = (c < 64) ? (W0 + c * 128 + kg * 8) : (W1 + (c - 64) * 128 + kg * 8);
    else            src = (kg < 8) ? (W0 + c * 64 + kg * 8)  : (W1 + c * 64 + (kg - 8) * 8);
    short8 v;
#pragma unroll
    for (int q = 0; q < 8; ++q) v[q] = (short)f2bf(src[q]);
    *(short8*)(&Wlds[c * 256 + ((kg * 16) ^ ((c & 7) << 4))]) = v;
  }
  __syncthreads();

  int w = t >> 6, l = t & 63;
  int lr = l & 15, lk = l >> 4;
  int r0 = blockIdx.x * 128 + w * 32;

  short8 afr[2][4];
#pragma unroll
  for (int set = 0; set < 2; ++set) {
    int row = r0 + set * 16 + lr;
    bool ok = row < N;
    if (a_fp32) {
#pragma unroll
      for (int kt = 0; kt < 4; ++kt) {
        short8 a = {0, 0, 0, 0, 0, 0, 0, 0};
        if (ok) {
          const unsigned char* bp = (const unsigned char*)(kt < 2 ? A0_ : A1_)
                + (size_t)row * (kt < 2 ? sa0b : sa1b) + 32 * lk + 128 * (kt & 1);
          f32x4 f0 = *(const f32x4*)bp;
          f32x4 f1 = *(const f32x4*)(bp + 16);
#pragma unroll
          for (int q = 0; q < 4; ++q) { a[q] = (short)f2bf(f0[q]); a[q + 4] = (short)f2bf(f1[q]); }
        }
        afr[set][kt] = a;
      }
    } else {
#pragma unroll
      for (int kt = 0; kt < 4; ++kt) {
        short8 a = {0, 0, 0, 0, 0, 0, 0, 0};
        if (ok) {
          const unsigned char* bp = (const unsigned char*)(kt < 2 ? A0_ : A1_)
                + (size_t)row * (kt < 2 ? sa0b : sa1b) + 16 * lk + 64 * (kt & 1);
          a = *(const short8*)bp;
        }
        afr[set][kt] = a;
      }
    }
  }

  f32x4 acc[2][8];
#pragma unroll
  for (int s = 0; s < 2; ++s)
#pragma unroll
    for (int c = 0; c < 8; ++c) acc[s][c] = (f32x4){0.f, 0.f, 0.f, 0.f};

#pragma unroll
  for (int ct = 0; ct < 8; ++ct) {
    int c = ct * 16 + lr;
    const unsigned char* rowp = &Wlds[c * 256];
    unsigned swz = (unsigned)((c & 7) << 4);
    short8 bfr[4];
#pragma unroll
    for (int kt = 0; kt < 4; ++kt)
      bfr[kt] = *(const short8*)(rowp + (((unsigned)(16 * lk + 64 * kt)) ^ swz));
#pragma unroll
    for (int kt = 0; kt < 4; ++kt) {
      acc[0][ct] = __builtin_amdgcn_mfma_f32_16x16x32_bf16(afr[0][kt], bfr[kt], acc[0][ct], 0, 0, 0);
      acc[1][ct] = __builtin_amdgcn_mfma_f32_16x16x32_bf16(afr[1][kt], bfr[kt], acc[1][ct], 0, 0, 0);
    }
  }

#pragma unroll
  for (int set = 0; set < 2; ++set) {
    int rbase = r0 + set * 16 + lk * 4;
#pragma unroll
    for (int ct = 0; ct < 8; ++ct) {
      int col = ct * 16 + lr;
      unsigned short* outp = (col < 64) ? out0 : out1;
      int so = (col < 64) ? so0 : so1;
      int cb = (col < 64) ? col : col - 64;
      float bv = bias ? bias[col] : 0.f;
#pragma unroll
      for (int j = 0; j < 4; ++j) {
        int row = rbase + j;
        if (row < N) {
          float v = acc[set][ct][j] + bv;
          if (relu) v = fmaxf(v, 0.f);
          outp[(size_t)row * so + cb] = f2bf(v);
        }
      }
    }
  }
}

// ---------------- CSR mean-aggregate, bf16 features, 2 nodes per wave ----------------
// out[v][c] = (sum_{u in adj[v]} feat[u][c]) * invdeg[v] (+ add[v][c]) (+ bias[c]) (relu?)
// 32-lane half-wave per node; lane sl handles channels 2*sl, 2*sl+1 (bf16x2 = 4B load).

__global__ __launch_bounds__(256) void agg_bf16(
    const unsigned short* __restrict__ feat, const int* __restrict__ adj,
    const int* __restrict__ rowoff, const float* __restrict__ invdeg,
    const unsigned short* __restrict__ add, const float* __restrict__ bias,
    void* __restrict__ outv, int N, int relu, int out_fp32)
{
  int t = threadIdx.x;
  int lane = t & 63;
  int half = lane >> 5, sl = lane & 31;
  int node = blockIdx.x * 8 + (t >> 6) * 2 + half;
  if (node >= N) return;
  int beg = rowoff[node], end = rowoff[node + 1];
  float s0 = 0.f, s1 = 0.f;
  int j = beg;
  for (; j + 4 <= end; j += 4) {
    int u0 = adj[j], u1 = adj[j + 1], u2 = adj[j + 2], u3 = adj[j + 3];
    unsigned p0 = *(const unsigned*)(feat + u0 * 64 + 2 * sl);
    unsigned p1 = *(const unsigned*)(feat + u1 * 64 + 2 * sl);
    unsigned p2 = *(const unsigned*)(feat + u2 * 64 + 2 * sl);
    unsigned p3 = *(const unsigned*)(feat + u3 * 64 + 2 * sl);
    s0 += __uint_as_float(p0 << 16); s1 += __uint_as_float(p0 & 0xffff0000u);
    s0 += __uint_as_float(p1 << 16); s1 += __uint_as_float(p1 & 0xffff0000u);
    s0 += __uint_as_float(p2 << 16); s1 += __uint_as_float(p2 & 0xffff0000u);
    s0 += __uint_as_float(p3 << 16); s1 += __uint_as_float(p3 & 0xffff0000u);
  }
  for (; j < end; ++j) {
    unsigned p = *(const unsigned*)(feat + adj[j] * 64 + 2 * sl);
    s0 += __uint_as_float(p << 16); s1 += __uint_as_float(p & 0xffff0000u);
  }
  float inv = invdeg[node];
  float v0 = s0 * inv, v1 = s1 * inv;
  if (add) {
    unsigned q = *(const unsigned*)(add + (size_t)node * 64 + 2 * sl);
    v0 += __uint_as_float(q << 16); v1 += __uint_as_float(q & 0xffff0000u);
  }
  if (bias) { v0 += bias[2 * sl]; v1 += bias[2 * sl + 1]; }
  if (relu) { v0 = fmaxf(v0, 0.f); v1 = fmaxf(v1, 0.f); }
  if (out_fp32) {
    float* o = (float*)outv + (size_t)node * 64 + 2 * sl;
    o[0] = v0; o[1] = v1;
  } else {
    unsigned pk = ((unsigned)f2bf(v1) << 16) | (unsigned)f2bf(v0);
    *(unsigned*)((unsigned short*)outv + (size_t)node * 64 + 2 * sl) = pk;
  }
}

// ---------------- launch ----------------

extern "C" void kernel_launch(void* const* d_in, const int* in_sizes, int n_in,
                              void* d_out, int out_size, void* d_ws, size_t ws_size,
                              hipStream_t stream) {
  const float* x   = (const float*)d_in[0];
  const int* edges = (const int*)d_in[1];
  const float* Wl1 = (const float*)d_in[2];
  const float* Wr1 = (const float*)d_in[3];
  const float* b1  = (const float*)d_in[4];
  const float* Wl2 = (const float*)d_in[5];
  const float* Wr2 = (const float*)d_in[6];
  const float* b2  = (const float*)d_in[7];
  const float* Wl3 = (const float*)d_in[8];
  const float* Wr3 = (const float*)d_in[9];
  const float* b3  = (const float*)d_in[10];

  int N = in_sizes[0] / 128;
  int E = in_sizes[1] / 2;
  const int* srcp = edges;
  const int* dstp = edges + E;
  int NBK = (N + BNODES - 1) / BNODES;   // 782 buckets for N=100k
  int NVB = NBK * REPS;                  // 25024 virtual buckets

  char* ws = (char*)d_ws;
  size_t off = 0;
  auto carve = [&](size_t bytes) -> void* {
    void* p = (void*)(ws + off);
    off += (bytes + 255) & ~(size_t)255;
    return p;
  };
  unsigned* bins = (unsigned*)carve((size_t)E * 4);
  int*   adj    = (int*)carve((size_t)E * 4);
  int*   rowoff = (int*)carve((size_t)(N + 1) * 4);
  int*   bcnt   = (int*)carve((size_t)NVB * 4);
  int*   boffb  = (int*)carve((size_t)(NVB + 1) * 4);
  int*   bcur   = (int*)carve((size_t)(NVB + 1) * 4);
  float* invdeg = (float*)carve((size_t)N * 4);
  unsigned short* B1 = (unsigned short*)carve((size_t)N * 64 * 2);
  unsigned short* B2 = (unsigned short*)carve((size_t)N * 64 * 2);
  unsigned short* B3 = (unsigned short*)carve((size_t)N * 64 * 2);
  unsigned short* P  = (unsigned short*)carve((size_t)N * 128 * 2);
  (void)ws_size;

  hipMemsetAsync(bcnt, 0, (size_t)NVB * 4, stream);

  int gridE = (E + THREADS - 1) / THREADS;

  bucket_count<<<gridE, THREADS, 0, stream>>>(dstp, bcnt, E);
  vb_scan<<<1, 1024, 0, stream>>>(bcnt, boffb, bcur, NVB);
  bin_fill<<<gridE, THREADS, 0, stream>>>(srcp, dstp, bcur, bins, E);
  node_offsets<<<NBK, THREADS, 0, stream>>>(bins, boffb, rowoff, invdeg, N, E);
  csr_fill<<<NBK, THREADS, 0, stream>>>(bins, boffb, rowoff, adj, N);

  int gridG = (N + 127) / 128;
  int gridA = (N + 7) / 8;

  // Layer 1 (transform-first): [z1|y1] = x @ [Wl1|Wr1]^T -> B1(z1), B2(y1)   [A fp32]
  mfma_gemm<<<gridG, THREADS, 0, stream>>>(x, x + 64, 512, 512, 1, Wl1, Wr1, 0,
                                           nullptr, 0, B1, B2, 64, 64, N);
  // h1 = relu(mean(z1) + y1 + b1) -> B3
  agg_bf16<<<gridA, THREADS, 0, stream>>>(B1, adj, rowoff, invdeg, B2, b1, B3, N, 1, 0);
  // mean2 = mean(h1) -> B1
  agg_bf16<<<gridA, THREADS, 0, stream>>>(B3, adj, rowoff, invdeg, nullptr, nullptr, B1, N, 0, 0);
  // Layer 2 (aggregate-first): h2 = relu([mean2|h1] @ [Wl2,Wr2]_K^T + b2) -> P
  mfma_gemm<<<gridG, THREADS, 0, stream>>>(B1, B3, 128, 128, 0, Wl2, Wr2, 1,
                                           b2, 1, P, P + 64, 128, 128, N);
  // Layer 3 (transform-first): [z3|y3] = h2 @ [Wl3|Wr3]^T -> B2(z3), B1(y3)
  mfma_gemm<<<gridG, THREADS, 0, stream>>>(P, P + 64, 256, 256, 0, Wl3, Wr3, 0,
                                           nullptr, 0, B2, B1, 64, 64, N);
  // out = mean(z3) + y3 + b3 -> d_out (fp32)
  agg_bf16<<<gridA, THREADS, 0, stream>>>(B2, adj, rowoff, invdeg, B1, b3, d_out, N, 0, 1);
}

// Round 6
// 257.437 us; speedup vs baseline: 9.0658x; 1.6222x over previous
//
#include <hip/hip_runtime.h>

#define THREADS 256
#define BSHIFT 7                    // 128 nodes per bucket
#define BNODES 128
#define CHUNK 8192                  // edges per binning block
#define BTHREADS 1024

typedef __attribute__((ext_vector_type(8))) short short8;
typedef __attribute__((ext_vector_type(4))) float f32x4;

__device__ inline unsigned short f2bf(float f) {
  unsigned int u = __float_as_uint(f);
  unsigned int r = u + 0x7fffu + ((u >> 16) & 1u);  // round-to-nearest-even
  return (unsigned short)(r >> 16);
}

// ---------------- block-aggregated binning ----------------
// Each block histograms CHUNK edges in LDS, then does ONE global atomic per
// non-empty bucket (reservation), then writes its records contiguously.

__global__ __launch_bounds__(BTHREADS) void count_block(
    const int* __restrict__ dst, int* __restrict__ bcnt, int E, int NBK) {
  __shared__ int lcnt[1024];
  int t = threadIdx.x;
  lcnt[t] = 0;
  __syncthreads();
  int base = blockIdx.x * CHUNK;
#pragma unroll
  for (int i = 0; i < CHUNK / BTHREADS; ++i) {
    int e = base + i * BTHREADS + t;
    if (e < E) atomicAdd(&lcnt[dst[e] >> BSHIFT], 1);
  }
  __syncthreads();
  if (t < NBK && lcnt[t] > 0) atomicAdd(&bcnt[t], lcnt[t]);
}

// single block: exclusive scan of bcnt[0..NBK) -> boff & bcur; boff[NBK]=E
__global__ __launch_bounds__(1024) void bucket_scan(const int* __restrict__ bcnt,
                                                    int* __restrict__ boff,
                                                    int* __restrict__ bcur, int NBK) {
  __shared__ int s[1024];
  int t = threadIdx.x;
  int v = (t < NBK) ? bcnt[t] : 0;
  s[t] = v;
  __syncthreads();
  for (int d = 1; d < 1024; d <<= 1) {
    int x = (t >= d) ? s[t - d] : 0;
    __syncthreads();
    s[t] += x;
    __syncthreads();
  }
  int excl = s[t] - v;
  if (t < NBK) { boff[t] = excl; bcur[t] = excl; }
  if (t == NBK) boff[t] = excl;  // == E
}

// records: (dst & 127) << 17 | src   (src < 2^17)
__global__ __launch_bounds__(BTHREADS) void fill_block(
    const int* __restrict__ src, const int* __restrict__ dst,
    int* __restrict__ bcur, unsigned* __restrict__ bins, int E, int NBK) {
  __shared__ int lcnt[1024];
  __shared__ int lbase[1024];
  int t = threadIdx.x;
  lcnt[t] = 0;
  __syncthreads();
  int base = blockIdx.x * CHUNK;
  unsigned recs[CHUNK / BTHREADS];
  int bkt[CHUNK / BTHREADS];
#pragma unroll
  for (int i = 0; i < CHUNK / BTHREADS; ++i) {
    int e = base + i * BTHREADS + t;
    if (e < E) {
      int d = dst[e];
      bkt[i] = d >> BSHIFT;
      recs[i] = ((unsigned)(d & (BNODES - 1)) << 17) | (unsigned)src[e];
      atomicAdd(&lcnt[bkt[i]], 1);
    } else bkt[i] = -1;
  }
  __syncthreads();
  if (t < NBK) {
    int c = lcnt[t];
    lbase[t] = (c > 0) ? atomicAdd(&bcur[t], c) : 0;
  }
  __syncthreads();
  lcnt[t] = 0;
  __syncthreads();
#pragma unroll
  for (int i = 0; i < CHUNK / BTHREADS; ++i) {
    if (bkt[i] >= 0) {
      int pos = lbase[bkt[i]] + atomicAdd(&lcnt[bkt[i]], 1);
      bins[pos] = recs[i];
    }
  }
}

// one block per bucket: per-node degree histogram -> rowoff (bucket-local scan) + invdeg
__global__ __launch_bounds__(256) void node_offsets(
    const unsigned* __restrict__ bins, const int* __restrict__ boff,
    int* __restrict__ rowoff, float* __restrict__ invdeg, int N, int E) {
  __shared__ int lcnt[BNODES];
  __shared__ int lscan[BNODES];
  int b = blockIdx.x, t = threadIdx.x;
  if (t < BNODES) lcnt[t] = 0;
  __syncthreads();
  int beg = boff[b], end = boff[b + 1];
  for (int i = beg + t; i < end; i += 256) atomicAdd(&lcnt[bins[i] >> 17], 1);
  __syncthreads();
  if (t < BNODES) lscan[t] = lcnt[t];
  __syncthreads();
  for (int d = 1; d < BNODES; d <<= 1) {
    int v = (t < BNODES && t >= d) ? lscan[t - d] : 0;
    __syncthreads();
    if (t < BNODES) lscan[t] += v;
    __syncthreads();
  }
  if (t < BNODES) {
    int g = b * BNODES + t;
    if (g < N) {
      rowoff[g] = beg + lscan[t] - lcnt[t];   // exclusive within bucket
      invdeg[g] = 1.0f / (float)(lcnt[t] > 1 ? lcnt[t] : 1);
    }
  }
  if (b == 0 && t == 0) rowoff[N] = E;
}

// one block per bucket: CSR fill with LDS cursors; adj writes land in a ~8KB window
__global__ __launch_bounds__(256) void csr_fill(
    const unsigned* __restrict__ bins, const int* __restrict__ boff,
    const int* __restrict__ rowoff, int* __restrict__ adj, int N) {
  __shared__ int lrow[BNODES];
  __shared__ int lcur[BNODES];
  int b = blockIdx.x, t = threadIdx.x;
  if (t < BNODES) {
    int g = b * BNODES + t;
    lrow[t] = (g < N) ? rowoff[g] : 0;
    lcur[t] = 0;
  }
  __syncthreads();
  int beg = boff[b], end = boff[b + 1];
  for (int i = beg + t; i < end; i += 256) {
    unsigned v = bins[i];
    int n = v >> 17;
    int pos = atomicAdd(&lcur[n], 1);
    adj[lrow[n] + pos] = (int)(v & 0x1FFFFu);
  }
}

// ---------------- MFMA GEMM: C[N,128] = A[N,128] @ Weff[128,128]^T ------------------
// wmode 0 (out-concat): Weff[c][k] = c<64 ? W0[c][k] (W0=[64,128]) : W1[c-64][k]
// wmode 1 (K-concat)  : Weff[c][k] = k<64 ? W0[c][k] (W0=[128,64]) : W1[c][k-64]

__global__ __launch_bounds__(256) void mfma_gemm(
    const void* __restrict__ A0_, const void* __restrict__ A1_, int sa0b, int sa1b, int a_fp32,
    const float* __restrict__ W0, const float* __restrict__ W1, int wmode,
    const float* __restrict__ bias, int relu,
    unsigned short* __restrict__ out0, unsigned short* __restrict__ out1,
    int so0, int so1, int N)
{
  __shared__ __align__(16) unsigned char Wlds[128 * 256];  // Weff[c][k] bf16, XOR-swizzled
  int t = threadIdx.x;

#pragma unroll
  for (int it = 0; it < 8; ++it) {
    int i = it * 256 + t;
    int c = i >> 4, kg = i & 15;
    const float* src;
    if (wmode == 0) src = (c < 64) ? (W0 + c * 128 + kg * 8) : (W1 + (c - 64) * 128 + kg * 8);
    else            src = (kg < 8) ? (W0 + c * 64 + kg * 8)  : (W1 + c * 64 + (kg - 8) * 8);
    short8 v;
#pragma unroll
    for (int q = 0; q < 8; ++q) v[q] = (short)f2bf(src[q]);
    *(short8*)(&Wlds[c * 256 + ((kg * 16) ^ ((c & 7) << 4))]) = v;
  }
  __syncthreads();

  int w = t >> 6, l = t & 63;
  int lr = l & 15, lk = l >> 4;
  int r0 = blockIdx.x * 128 + w * 32;

  short8 afr[2][4];
#pragma unroll
  for (int set = 0; set < 2; ++set) {
    int row = r0 + set * 16 + lr;
    bool ok = row < N;
    if (a_fp32) {
#pragma unroll
      for (int kt = 0; kt < 4; ++kt) {
        short8 a = {0, 0, 0, 0, 0, 0, 0, 0};
        if (ok) {
          const unsigned char* bp = (const unsigned char*)(kt < 2 ? A0_ : A1_)
                + (size_t)row * (kt < 2 ? sa0b : sa1b) + 32 * lk + 128 * (kt & 1);
          f32x4 f0 = *(const f32x4*)bp;
          f32x4 f1 = *(const f32x4*)(bp + 16);
#pragma unroll
          for (int q = 0; q < 4; ++q) { a[q] = (short)f2bf(f0[q]); a[q + 4] = (short)f2bf(f1[q]); }
        }
        afr[set][kt] = a;
      }
    } else {
#pragma unroll
      for (int kt = 0; kt < 4; ++kt) {
        short8 a = {0, 0, 0, 0, 0, 0, 0, 0};
        if (ok) {
          const unsigned char* bp = (const unsigned char*)(kt < 2 ? A0_ : A1_)
                + (size_t)row * (kt < 2 ? sa0b : sa1b) + 16 * lk + 64 * (kt & 1);
          a = *(const short8*)bp;
        }
        afr[set][kt] = a;
      }
    }
  }

  f32x4 acc[2][8];
#pragma unroll
  for (int s = 0; s < 2; ++s)
#pragma unroll
    for (int c = 0; c < 8; ++c) acc[s][c] = (f32x4){0.f, 0.f, 0.f, 0.f};

#pragma unroll
  for (int ct = 0; ct < 8; ++ct) {
    int c = ct * 16 + lr;
    const unsigned char* rowp = &Wlds[c * 256];
    unsigned swz = (unsigned)((c & 7) << 4);
    short8 bfr[4];
#pragma unroll
    for (int kt = 0; kt < 4; ++kt)
      bfr[kt] = *(const short8*)(rowp + (((unsigned)(16 * lk + 64 * kt)) ^ swz));
#pragma unroll
    for (int kt = 0; kt < 4; ++kt) {
      acc[0][ct] = __builtin_amdgcn_mfma_f32_16x16x32_bf16(afr[0][kt], bfr[kt], acc[0][ct], 0, 0, 0);
      acc[1][ct] = __builtin_amdgcn_mfma_f32_16x16x32_bf16(afr[1][kt], bfr[kt], acc[1][ct], 0, 0, 0);
    }
  }

#pragma unroll
  for (int set = 0; set < 2; ++set) {
    int rbase = r0 + set * 16 + lk * 4;
#pragma unroll
    for (int ct = 0; ct < 8; ++ct) {
      int col = ct * 16 + lr;
      unsigned short* outp = (col < 64) ? out0 : out1;
      int so = (col < 64) ? so0 : so1;
      int cb = (col < 64) ? col : col - 64;
      float bv = bias ? bias[col] : 0.f;
#pragma unroll
      for (int j = 0; j < 4; ++j) {
        int row = rbase + j;
        if (row < N) {
          float v = acc[set][ct][j] + bv;
          if (relu) v = fmaxf(v, 0.f);
          outp[(size_t)row * so + cb] = f2bf(v);
        }
      }
    }
  }
}

// ---------------- CSR mean-aggregate, bf16 features, 2 nodes per wave ----------------
// out[v][c] = (sum_{u in adj[v]} feat[u][c]) * invdeg[v] (+ add[v][c]) (+ bias[c]) (relu?)
// 32-lane half-wave per node; lane sl handles channels 2*sl, 2*sl+1 (bf16x2 = 4B load).

__global__ __launch_bounds__(256) void agg_bf16(
    const unsigned short* __restrict__ feat, const int* __restrict__ adj,
    const int* __restrict__ rowoff, const float* __restrict__ invdeg,
    const unsigned short* __restrict__ add, const float* __restrict__ bias,
    void* __restrict__ outv, int N, int relu, int out_fp32)
{
  int t = threadIdx.x;
  int lane = t & 63;
  int half = lane >> 5, sl = lane & 31;
  int node = blockIdx.x * 8 + (t >> 6) * 2 + half;
  if (node >= N) return;
  int beg = rowoff[node], end = rowoff[node + 1];
  float s0 = 0.f, s1 = 0.f;
  int j = beg;
  for (; j + 8 <= end; j += 8) {
    unsigned p[8];
#pragma unroll
    for (int u = 0; u < 8; ++u) p[u] = *(const unsigned*)(feat + adj[j + u] * 64 + 2 * sl);
#pragma unroll
    for (int u = 0; u < 8; ++u) {
      s0 += __uint_as_float(p[u] << 16);
      s1 += __uint_as_float(p[u] & 0xffff0000u);
    }
  }
  for (; j < end; ++j) {
    unsigned p = *(const unsigned*)(feat + adj[j] * 64 + 2 * sl);
    s0 += __uint_as_float(p << 16); s1 += __uint_as_float(p & 0xffff0000u);
  }
  float inv = invdeg[node];
  float v0 = s0 * inv, v1 = s1 * inv;
  if (add) {
    unsigned q = *(const unsigned*)(add + (size_t)node * 64 + 2 * sl);
    v0 += __uint_as_float(q << 16); v1 += __uint_as_float(q & 0xffff0000u);
  }
  if (bias) { v0 += bias[2 * sl]; v1 += bias[2 * sl + 1]; }
  if (relu) { v0 = fmaxf(v0, 0.f); v1 = fmaxf(v1, 0.f); }
  if (out_fp32) {
    float* o = (float*)outv + (size_t)node * 64 + 2 * sl;
    o[0] = v0; o[1] = v1;
  } else {
    unsigned pk = ((unsigned)f2bf(v1) << 16) | (unsigned)f2bf(v0);
    *(unsigned*)((unsigned short*)outv + (size_t)node * 64 + 2 * sl) = pk;
  }
}

// ---------------- launch ----------------

extern "C" void kernel_launch(void* const* d_in, const int* in_sizes, int n_in,
                              void* d_out, int out_size, void* d_ws, size_t ws_size,
                              hipStream_t stream) {
  const float* x   = (const float*)d_in[0];
  const int* edges = (const int*)d_in[1];
  const float* Wl1 = (const float*)d_in[2];
  const float* Wr1 = (const float*)d_in[3];
  const float* b1  = (const float*)d_in[4];
  const float* Wl2 = (const float*)d_in[5];
  const float* Wr2 = (const float*)d_in[6];
  const float* b2  = (const float*)d_in[7];
  const float* Wl3 = (const float*)d_in[8];
  const float* Wr3 = (const float*)d_in[9];
  const float* b3  = (const float*)d_in[10];

  int N = in_sizes[0] / 128;
  int E = in_sizes[1] / 2;
  const int* srcp = edges;
  const int* dstp = edges + E;
  int NBK = (N + BNODES - 1) / BNODES;   // 782 buckets for N=100k

  char* ws = (char*)d_ws;
  size_t off = 0;
  auto carve = [&](size_t bytes) -> void* {
    void* p = (void*)(ws + off);
    off += (bytes + 255) & ~(size_t)255;
    return p;
  };
  unsigned* bins = (unsigned*)carve((size_t)E * 4);
  int*   adj    = (int*)carve((size_t)E * 4);
  int*   rowoff = (int*)carve((size_t)(N + 1) * 4);
  int*   bcnt   = (int*)carve(1024 * 4);
  int*   boffb  = (int*)carve(1025 * 4);
  int*   bcur   = (int*)carve(1024 * 4);
  float* invdeg = (float*)carve((size_t)N * 4);
  unsigned short* B1 = (unsigned short*)carve((size_t)N * 64 * 2);
  unsigned short* B2 = (unsigned short*)carve((size_t)N * 64 * 2);
  unsigned short* B3 = (unsigned short*)carve((size_t)N * 64 * 2);
  unsigned short* P  = (unsigned short*)carve((size_t)N * 128 * 2);
  (void)ws_size;

  hipMemsetAsync(bcnt, 0, 1024 * 4, stream);

  int gridF = (E + CHUNK - 1) / CHUNK;   // 196 blocks

  count_block<<<gridF, BTHREADS, 0, stream>>>(dstp, bcnt, E, NBK);
  bucket_scan<<<1, 1024, 0, stream>>>(bcnt, boffb, bcur, NBK);
  fill_block<<<gridF, BTHREADS, 0, stream>>>(srcp, dstp, bcur, bins, E, NBK);
  node_offsets<<<NBK, THREADS, 0, stream>>>(bins, boffb, rowoff, invdeg, N, E);
  csr_fill<<<NBK, THREADS, 0, stream>>>(bins, boffb, rowoff, adj, N);

  int gridG = (N + 127) / 128;
  int gridA = (N + 7) / 8;

  // Layer 1 (transform-first): [z1|y1] = x @ [Wl1|Wr1]^T -> B1(z1), B2(y1)   [A fp32]
  mfma_gemm<<<gridG, THREADS, 0, stream>>>(x, x + 64, 512, 512, 1, Wl1, Wr1, 0,
                                           nullptr, 0, B1, B2, 64, 64, N);
  // h1 = relu(mean(z1) + y1 + b1) -> B3
  agg_bf16<<<gridA, THREADS, 0, stream>>>(B1, adj, rowoff, invdeg, B2, b1, B3, N, 1, 0);
  // mean2 = mean(h1) -> B1
  agg_bf16<<<gridA, THREADS, 0, stream>>>(B3, adj, rowoff, invdeg, nullptr, nullptr, B1, N, 0, 0);
  // Layer 2 (aggregate-first): h2 = relu([mean2|h1] @ [Wl2,Wr2]_K^T + b2) -> P
  mfma_gemm<<<gridG, THREADS, 0, stream>>>(B1, B3, 128, 128, 0, Wl2, Wr2, 1,
                                           b2, 1, P, P + 64, 128, 128, N);
  // Layer 3 (transform-first): [z3|y3] = h2 @ [Wl3|Wr3]^T -> B2(z3), B1(y3)
  mfma_gemm<<<gridG, THREADS, 0, stream>>>(P, P + 64, 256, 256, 0, Wl3, Wr3, 0,
                                           nullptr, 0, B2, B1, 64, 64, N);
  // out = mean(z3) + y3 + b3 -> d_out (fp32)
  agg_bf16<<<gridA, THREADS, 0, stream>>>(B2, adj, rowoff, invdeg, B1, b3, d_out, N, 0, 1);
}

// Round 7
// 228.318 us; speedup vs baseline: 10.2221x; 1.1275x over previous
//
#include <hip/hip_runtime.h>

#define THREADS 256
#define BSHIFT 7                    // 128 nodes per bucket
#define BNODES 128
#define CHUNK 8192                  // edges per binning block
#define BTHREADS 1024

typedef __attribute__((ext_vector_type(8))) short short8;
typedef __attribute__((ext_vector_type(4))) float f32x4;

__device__ inline unsigned short f2bf(float f) {
  unsigned int u = __float_as_uint(f);
  unsigned int r = u + 0x7fffu + ((u >> 16) & 1u);  // round-to-nearest-even
  return (unsigned short)(r >> 16);
}

// ---------------- block-aggregated binning ----------------
// Each block histograms CHUNK edges in LDS, then does ONE global atomic per
// non-empty bucket (reservation), then writes its records contiguously.

__global__ __launch_bounds__(BTHREADS) void count_block(
    const int* __restrict__ dst, int* __restrict__ bcnt, int E, int NBK) {
  __shared__ int lcnt[1024];
  int t = threadIdx.x;
  lcnt[t] = 0;
  __syncthreads();
  int base = blockIdx.x * CHUNK;
#pragma unroll
  for (int i = 0; i < CHUNK / BTHREADS; ++i) {
    int e = base + i * BTHREADS + t;
    if (e < E) atomicAdd(&lcnt[dst[e] >> BSHIFT], 1);
  }
  __syncthreads();
  if (t < NBK && lcnt[t] > 0) atomicAdd(&bcnt[t], lcnt[t]);
}

// single block: exclusive scan of bcnt[0..NBK) -> boff & bcur; boff[NBK]=E
__global__ __launch_bounds__(1024) void bucket_scan(const int* __restrict__ bcnt,
                                                    int* __restrict__ boff,
                                                    int* __restrict__ bcur, int NBK) {
  __shared__ int s[1024];
  int t = threadIdx.x;
  int v = (t < NBK) ? bcnt[t] : 0;
  s[t] = v;
  __syncthreads();
  for (int d = 1; d < 1024; d <<= 1) {
    int x = (t >= d) ? s[t - d] : 0;
    __syncthreads();
    s[t] += x;
    __syncthreads();
  }
  int excl = s[t] - v;
  if (t < NBK) { boff[t] = excl; bcur[t] = excl; }
  if (t == NBK) boff[t] = excl;  // == E
}

// records: (dst & 127) << 17 | src   (src < 2^17)
__global__ __launch_bounds__(BTHREADS) void fill_block(
    const int* __restrict__ src, const int* __restrict__ dst,
    int* __restrict__ bcur, unsigned* __restrict__ bins, int E, int NBK) {
  __shared__ int lcnt[1024];
  __shared__ int lbase[1024];
  int t = threadIdx.x;
  lcnt[t] = 0;
  __syncthreads();
  int base = blockIdx.x * CHUNK;
  unsigned recs[CHUNK / BTHREADS];
  int bkt[CHUNK / BTHREADS];
#pragma unroll
  for (int i = 0; i < CHUNK / BTHREADS; ++i) {
    int e = base + i * BTHREADS + t;
    if (e < E) {
      int d = dst[e];
      bkt[i] = d >> BSHIFT;
      recs[i] = ((unsigned)(d & (BNODES - 1)) << 17) | (unsigned)src[e];
      atomicAdd(&lcnt[bkt[i]], 1);
    } else bkt[i] = -1;
  }
  __syncthreads();
  if (t < NBK) {
    int c = lcnt[t];
    lbase[t] = (c > 0) ? atomicAdd(&bcur[t], c) : 0;
  }
  __syncthreads();
  lcnt[t] = 0;
  __syncthreads();
#pragma unroll
  for (int i = 0; i < CHUNK / BTHREADS; ++i) {
    if (bkt[i] >= 0) {
      int pos = lbase[bkt[i]] + atomicAdd(&lcnt[bkt[i]], 1);
      bins[pos] = recs[i];
    }
  }
}

// one block per bucket (fused): histogram -> LDS scan -> rowoff/invdeg -> CSR scatter.
// adj writes for a bucket land in a contiguous ~8KB window.
__global__ __launch_bounds__(256) void bucket_csr(
    const unsigned* __restrict__ bins, const int* __restrict__ boff,
    int* __restrict__ rowoff, float* __restrict__ invdeg,
    int* __restrict__ adj, int N, int E) {
  __shared__ int lcnt[BNODES];
  __shared__ int lscan[BNODES];
  __shared__ int lrow[BNODES];
  __shared__ int lcur[BNODES];
  int b = blockIdx.x, t = threadIdx.x;
  if (t < BNODES) { lcnt[t] = 0; lcur[t] = 0; }
  __syncthreads();
  int beg = boff[b], end = boff[b + 1];
  for (int i = beg + t; i < end; i += 256) atomicAdd(&lcnt[bins[i] >> 17], 1);
  __syncthreads();
  if (t < BNODES) lscan[t] = lcnt[t];
  __syncthreads();
  for (int d = 1; d < BNODES; d <<= 1) {
    int v = (t < BNODES && t >= d) ? lscan[t - d] : 0;
    __syncthreads();
    if (t < BNODES) lscan[t] += v;
    __syncthreads();
  }
  if (t < BNODES) {
    int ro = beg + lscan[t] - lcnt[t];   // exclusive within bucket
    lrow[t] = ro;
    int g = b * BNODES + t;
    if (g < N) {
      rowoff[g] = ro;
      invdeg[g] = 1.0f / (float)(lcnt[t] > 1 ? lcnt[t] : 1);
    }
  }
  __syncthreads();
  for (int i = beg + t; i < end; i += 256) {
    unsigned v = bins[i];
    int n = v >> 17;
    int pos = atomicAdd(&lcur[n], 1);
    adj[lrow[n] + pos] = (int)(v & 0x1FFFFu);
  }
  if (b == 0 && t == 0) rowoff[N] = E;
}

// ---------------- MFMA GEMM: C[N,128] = A[N,128] @ Weff[128,128]^T ------------------
// wmode 0 (out-concat): Weff[c][k] = c<64 ? W0[c][k] (W0=[64,128]) : W1[c-64][k]
// wmode 1 (K-concat)  : Weff[c][k] = k<64 ? W0[c][k] (W0=[128,64]) : W1[c][k-64]

__global__ __launch_bounds__(256) void mfma_gemm(
    const void* __restrict__ A0_, const void* __restrict__ A1_, int sa0b, int sa1b, int a_fp32,
    const float* __restrict__ W0, const float* __restrict__ W1, int wmode,
    const float* __restrict__ bias, int relu,
    unsigned short* __restrict__ out0, unsigned short* __restrict__ out1,
    int so0, int so1, int N)
{
  __shared__ __align__(16) unsigned char Wlds[128 * 256];  // Weff[c][k] bf16, XOR-swizzled
  int t = threadIdx.x;

#pragma unroll
  for (int it = 0; it < 8; ++it) {
    int i = it * 256 + t;
    int c = i >> 4, kg = i & 15;
    const float* src;
    if (wmode == 0) src = (c < 64) ? (W0 + c * 128 + kg * 8) : (W1 + (c - 64) * 128 + kg * 8);
    else            src = (kg < 8) ? (W0 + c * 64 + kg * 8)  : (W1 + c * 64 + (kg - 8) * 8);
    short8 v;
#pragma unroll
    for (int q = 0; q < 8; ++q) v[q] = (short)f2bf(src[q]);
    *(short8*)(&Wlds[c * 256 + ((kg * 16) ^ ((c & 7) << 4))]) = v;
  }
  __syncthreads();

  int w = t >> 6, l = t & 63;
  int lr = l & 15, lk = l >> 4;
  int r0 = blockIdx.x * 128 + w * 32;

  short8 afr[2][4];
#pragma unroll
  for (int set = 0; set < 2; ++set) {
    int row = r0 + set * 16 + lr;
    bool ok = row < N;
    if (a_fp32) {
#pragma unroll
      for (int kt = 0; kt < 4; ++kt) {
        short8 a = {0, 0, 0, 0, 0, 0, 0, 0};
        if (ok) {
          const unsigned char* bp = (const unsigned char*)(kt < 2 ? A0_ : A1_)
                + (size_t)row * (kt < 2 ? sa0b : sa1b) + 32 * lk + 128 * (kt & 1);
          f32x4 f0 = *(const f32x4*)bp;
          f32x4 f1 = *(const f32x4*)(bp + 16);
#pragma unroll
          for (int q = 0; q < 4; ++q) { a[q] = (short)f2bf(f0[q]); a[q + 4] = (short)f2bf(f1[q]); }
        }
        afr[set][kt] = a;
      }
    } else {
#pragma unroll
      for (int kt = 0; kt < 4; ++kt) {
        short8 a = {0, 0, 0, 0, 0, 0, 0, 0};
        if (ok) {
          const unsigned char* bp = (const unsigned char*)(kt < 2 ? A0_ : A1_)
                + (size_t)row * (kt < 2 ? sa0b : sa1b) + 16 * lk + 64 * (kt & 1);
          a = *(const short8*)bp;
        }
        afr[set][kt] = a;
      }
    }
  }

  f32x4 acc[2][8];
#pragma unroll
  for (int s = 0; s < 2; ++s)
#pragma unroll
    for (int c = 0; c < 8; ++c) acc[s][c] = (f32x4){0.f, 0.f, 0.f, 0.f};

#pragma unroll
  for (int ct = 0; ct < 8; ++ct) {
    int c = ct * 16 + lr;
    const unsigned char* rowp = &Wlds[c * 256];
    unsigned swz = (unsigned)((c & 7) << 4);
    short8 bfr[4];
#pragma unroll
    for (int kt = 0; kt < 4; ++kt)
      bfr[kt] = *(const short8*)(rowp + (((unsigned)(16 * lk + 64 * kt)) ^ swz));
#pragma unroll
    for (int kt = 0; kt < 4; ++kt) {
      acc[0][ct] = __builtin_amdgcn_mfma_f32_16x16x32_bf16(afr[0][kt], bfr[kt], acc[0][ct], 0, 0, 0);
      acc[1][ct] = __builtin_amdgcn_mfma_f32_16x16x32_bf16(afr[1][kt], bfr[kt], acc[1][ct], 0, 0, 0);
    }
  }

#pragma unroll
  for (int set = 0; set < 2; ++set) {
    int rbase = r0 + set * 16 + lk * 4;
#pragma unroll
    for (int ct = 0; ct < 8; ++ct) {
      int col = ct * 16 + lr;
      unsigned short* outp = (col < 64) ? out0 : out1;
      int so = (col < 64) ? so0 : so1;
      int cb = (col < 64) ? col : col - 64;
      float bv = bias ? bias[col] : 0.f;
#pragma unroll
      for (int j = 0; j < 4; ++j) {
        int row = rbase + j;
        if (row < N) {
          float v = acc[set][ct][j] + bv;
          if (relu) v = fmaxf(v, 0.f);
          outp[(size_t)row * so + cb] = f2bf(v);
        }
      }
    }
  }
}

// ---------------- CSR mean-aggregate, bf16 features, 4 nodes per wave ----------------
// out[v][c] = (sum_{u in adj[v]} feat[u][c]) * invdeg[v] (+ add[v][c]) (+ bias[c]) (relu?)
// 16-lane quarter-wave per node; lane sl handles channels 4*sl..4*sl+3 (8B loads).

__global__ __launch_bounds__(256) void agg_bf16(
    const unsigned short* __restrict__ feat, const int* __restrict__ adj,
    const int* __restrict__ rowoff, const float* __restrict__ invdeg,
    const unsigned short* __restrict__ add, const float* __restrict__ bias,
    void* __restrict__ outv, int N, int relu, int out_fp32)
{
  int t = threadIdx.x;
  int lane = t & 63;
  int q = lane >> 4, sl = lane & 15;
  int node = blockIdx.x * 16 + (t >> 6) * 4 + q;
  if (node >= N) return;
  int beg = rowoff[node], end = rowoff[node + 1];
  float s0 = 0.f, s1 = 0.f, s2 = 0.f, s3 = 0.f;
  int j = beg;
  for (; j + 8 <= end; j += 8) {
    unsigned long long p[8];
#pragma unroll
    for (int u = 0; u < 8; ++u)
      p[u] = *(const unsigned long long*)(feat + (size_t)adj[j + u] * 64 + 4 * sl);
#pragma unroll
    for (int u = 0; u < 8; ++u) {
      unsigned lo = (unsigned)p[u], hi = (unsigned)(p[u] >> 32);
      s0 += __uint_as_float(lo << 16); s1 += __uint_as_float(lo & 0xffff0000u);
      s2 += __uint_as_float(hi << 16); s3 += __uint_as_float(hi & 0xffff0000u);
    }
  }
  for (; j < end; ++j) {
    unsigned long long p = *(const unsigned long long*)(feat + (size_t)adj[j] * 64 + 4 * sl);
    unsigned lo = (unsigned)p, hi = (unsigned)(p >> 32);
    s0 += __uint_as_float(lo << 16); s1 += __uint_as_float(lo & 0xffff0000u);
    s2 += __uint_as_float(hi << 16); s3 += __uint_as_float(hi & 0xffff0000u);
  }
  float inv = invdeg[node];
  float v0 = s0 * inv, v1 = s1 * inv, v2 = s2 * inv, v3 = s3 * inv;
  if (add) {
    unsigned long long qq = *(const unsigned long long*)(add + (size_t)node * 64 + 4 * sl);
    unsigned lo = (unsigned)qq, hi = (unsigned)(qq >> 32);
    v0 += __uint_as_float(lo << 16); v1 += __uint_as_float(lo & 0xffff0000u);
    v2 += __uint_as_float(hi << 16); v3 += __uint_as_float(hi & 0xffff0000u);
  }
  if (bias) {
    f32x4 bv = *(const f32x4*)(bias + 4 * sl);
    v0 += bv[0]; v1 += bv[1]; v2 += bv[2]; v3 += bv[3];
  }
  if (relu) {
    v0 = fmaxf(v0, 0.f); v1 = fmaxf(v1, 0.f);
    v2 = fmaxf(v2, 0.f); v3 = fmaxf(v3, 0.f);
  }
  if (out_fp32) {
    f32x4 o = {v0, v1, v2, v3};
    *(f32x4*)((float*)outv + (size_t)node * 64 + 4 * sl) = o;
  } else {
    unsigned pk0 = ((unsigned)f2bf(v1) << 16) | (unsigned)f2bf(v0);
    unsigned pk1 = ((unsigned)f2bf(v3) << 16) | (unsigned)f2bf(v2);
    unsigned long long pk = ((unsigned long long)pk1 << 32) | pk0;
    *(unsigned long long*)((unsigned short*)outv + (size_t)node * 64 + 4 * sl) = pk;
  }
}

// ---------------- launch ----------------

extern "C" void kernel_launch(void* const* d_in, const int* in_sizes, int n_in,
                              void* d_out, int out_size, void* d_ws, size_t ws_size,
                              hipStream_t stream) {
  const float* x   = (const float*)d_in[0];
  const int* edges = (const int*)d_in[1];
  const float* Wl1 = (const float*)d_in[2];
  const float* Wr1 = (const float*)d_in[3];
  const float* b1  = (const float*)d_in[4];
  const float* Wl2 = (const float*)d_in[5];
  const float* Wr2 = (const float*)d_in[6];
  const float* b2  = (const float*)d_in[7];
  const float* Wl3 = (const float*)d_in[8];
  const float* Wr3 = (const float*)d_in[9];
  const float* b3  = (const float*)d_in[10];

  int N = in_sizes[0] / 128;
  int E = in_sizes[1] / 2;
  const int* srcp = edges;
  const int* dstp = edges + E;
  int NBK = (N + BNODES - 1) / BNODES;   // 782 buckets for N=100k

  char* ws = (char*)d_ws;
  size_t off = 0;
  auto carve = [&](size_t bytes) -> void* {
    void* p = (void*)(ws + off);
    off += (bytes + 255) & ~(size_t)255;
    return p;
  };
  unsigned* bins = (unsigned*)carve((size_t)E * 4);
  int*   adj    = (int*)carve((size_t)E * 4);
  int*   rowoff = (int*)carve((size_t)(N + 1) * 4);
  int*   bcnt   = (int*)carve(1024 * 4);
  int*   boffb  = (int*)carve(1025 * 4);
  int*   bcur   = (int*)carve(1024 * 4);
  float* invdeg = (float*)carve((size_t)N * 4);
  unsigned short* B1 = (unsigned short*)carve((size_t)N * 64 * 2);
  unsigned short* B2 = (unsigned short*)carve((size_t)N * 64 * 2);
  unsigned short* B3 = (unsigned short*)carve((size_t)N * 64 * 2);
  unsigned short* P  = (unsigned short*)carve((size_t)N * 128 * 2);
  (void)ws_size;

  hipMemsetAsync(bcnt, 0, 1024 * 4, stream);

  int gridF = (E + CHUNK - 1) / CHUNK;   // 196 blocks

  count_block<<<gridF, BTHREADS, 0, stream>>>(dstp, bcnt, E, NBK);
  bucket_scan<<<1, 1024, 0, stream>>>(bcnt, boffb, bcur, NBK);
  fill_block<<<gridF, BTHREADS, 0, stream>>>(srcp, dstp, bcur, bins, E, NBK);
  bucket_csr<<<NBK, THREADS, 0, stream>>>(bins, boffb, rowoff, invdeg, adj, N, E);

  int gridG = (N + 127) / 128;
  int gridA = (N + 15) / 16;

  // Layer 1 (transform-first): [z1|y1] = x @ [Wl1|Wr1]^T -> B1(z1), B2(y1)   [A fp32]
  mfma_gemm<<<gridG, THREADS, 0, stream>>>(x, x + 64, 512, 512, 1, Wl1, Wr1, 0,
                                           nullptr, 0, B1, B2, 64, 64, N);
  // h1 = relu(mean(z1) + y1 + b1) -> B3
  agg_bf16<<<gridA, THREADS, 0, stream>>>(B1, adj, rowoff, invdeg, B2, b1, B3, N, 1, 0);
  // mean2 = mean(h1) -> B1
  agg_bf16<<<gridA, THREADS, 0, stream>>>(B3, adj, rowoff, invdeg, nullptr, nullptr, B1, N, 0, 0);
  // Layer 2 (aggregate-first): h2 = relu([mean2|h1] @ [Wl2,Wr2]_K^T + b2) -> P
  mfma_gemm<<<gridG, THREADS, 0, stream>>>(B1, B3, 128, 128, 0, Wl2, Wr2, 1,
                                           b2, 1, P, P + 64, 128, 128, N);
  // Layer 3 (transform-first): [z3|y3] = h2 @ [Wl3|Wr3]^T -> B2(z3), B1(y3)
  mfma_gemm<<<gridG, THREADS, 0, stream>>>(P, P + 64, 256, 256, 0, Wl3, Wr3, 0,
                                           nullptr, 0, B2, B1, 64, 64, N);
  // out = mean(z3) + y3 + b3 -> d_out (fp32)
  agg_bf16<<<gridA, THREADS, 0, stream>>>(B2, adj, rowoff, invdeg, B1, b3, d_out, N, 0, 1);
}